// Round 5
// baseline (134.209 us; speedup 1.0000x reference)
//
#include <hip/hip_runtime.h>
#include <hip/hip_bf16.h>
#include <math.h>

#define D 32
#define CAP 64      // bucket capacity (mid path up to CAP, full-scan beyond)
#define PRE 24      // prefetch fast-path capacity (max Poisson(8) over 2048 ~ 22)
#define BT 256      // threads per block

typedef __attribute__((ext_vector_type(8))) short short8v;
typedef __attribute__((ext_vector_type(4))) float float4v;

static __device__ __forceinline__ unsigned short f2bf(float f) {
    union { __hip_bfloat16 h; unsigned short u; } cv;
    cv.h = __float2bfloat16(f);
    return cv.u;
}
static __device__ __forceinline__ float bf2f(unsigned short u) {
    union { float f; unsigned int i; } c;
    c.i = ((unsigned int)u) << 16;
    return c.f;
}

// grid barrier: monotonic counter, zeroed by the memset node before each replay
static __device__ __forceinline__ void gbar(int* ctr, int nblk) {
    __syncthreads();                       // drains this block's vmem (compiler emits vmcnt(0))
    if (threadIdx.x == 0) {
        __threadfence();                   // release: publish this block's writes
        atomicAdd(ctr, 1);
        while (atomicAdd(ctr, 0) < nblk) __builtin_amdgcn_s_sleep(2);
        __threadfence();                   // acquire: invalidate stale cache lines
    }
    __syncthreads();
}

__global__ void __launch_bounds__(BT, 2)
k_mega(const float* __restrict__ x, const float* __restrict__ kw,
       const float* __restrict__ p_in, const int* __restrict__ tgt,
       unsigned short* __restrict__ xnb, unsigned short* __restrict__ qb,
       float* __restrict__ w, int* __restrict__ cnt, int* __restrict__ list2d,
       int* __restrict__ bar, float* __restrict__ part, int* __restrict__ done,
       float* __restrict__ out, int N, int C, float dval, int nblk)
{
    int tid = threadIdx.x, b = blockIdx.x;
    int lane = tid & 63, wv = tid >> 6;

    // ======== P0: normalize samples -> bf16 xnb, bucket-scatter indices ========
    {
        int g = b * BT + tid;              // nblk*BT == N*8 exactly
        int i = g >> 3, q = g & 7;
        if (i < N) {
            float4 v = ((const float4*)(x + (size_t)i * D))[q];
            float ss = v.x*v.x + v.y*v.y + v.z*v.z + v.w*v.w;
            ss += __shfl_xor(ss, 1); ss += __shfl_xor(ss, 2); ss += __shfl_xor(ss, 4);
            float nrm = fmaxf(sqrtf(ss), 1e-8f);
            ushort4 ob;
            ob.x = f2bf(v.x / nrm); ob.y = f2bf(v.y / nrm);
            ob.z = f2bf(v.z / nrm); ob.w = f2bf(v.w / nrm);
            ((ushort4*)(xnb + (size_t)i * D))[q] = ob;
            if (q == 0) {
                int t = tgt[i];
                int pos = atomicAdd(&cnt[t], 1);
                if (pos < CAP) list2d[t * CAP + pos] = i;   // unordered; P1 sorts
            }
        }
    }
    gbar(&bar[0], nblk);

    // ======== P1: per-class sequential EMA chain -> qb (kappa folded), w ========
    {
        int c = b * (BT / 64) + wv;        // one class per wave; == C waves exactly
        if (c < C) {
            int e = lane & 31;             // lanes 32-63 mirror 0-31
            float p = p_in[(size_t)c * D + e];
            int count = cnt[c];
            if (count <= PRE) {
                // rank-sort indices in-wave, prefetch all vectors, ALU-only chain
                int idx = (lane < count) ? list2d[c * CAP + lane] : 0x7fffffff;
                int rank = 0;
                for (int j = 0; j < count; ++j) {
                    int v = __shfl(idx, j);
                    rank += (v < idx) ? 1 : 0;
                }
                int sorted = 0;
                for (int j = 0; j < count; ++j) {
                    int v = __shfl(idx, j); int r = __shfl(rank, j);
                    if (r == lane) sorted = v;
                }
                float vals[PRE];
#pragma unroll
                for (int it = 0; it < PRE; ++it)
                    if (it < count) {
                        int si = __shfl(sorted, it);
                        vals[it] = bf2f(xnb[(size_t)si * D + e]);   // independent loads
                    }
#pragma unroll
                for (int it = 0; it < PRE; ++it)
                    if (it < count) {
                        p = fmaf(0.05f, vals[it], 0.95f * p);
                        float pp = p * p;
                        pp += __shfl_xor(pp, 16); pp += __shfl_xor(pp, 8); pp += __shfl_xor(pp, 4);
                        pp += __shfl_xor(pp, 2);  pp += __shfl_xor(pp, 1);
                        p = p / fmaxf(sqrtf(pp), 1e-12f);
                    }
            } else if (count <= CAP) {
                // exact mid path: min-extract ordered chain (dependent loads)
                int idx = (lane < count) ? list2d[c * CAP + lane] : 0x7fffffff;
                for (int it = 0; it < count; ++it) {
                    int mn = idx;
                    mn = min(mn, __shfl_xor(mn, 32)); mn = min(mn, __shfl_xor(mn, 16));
                    mn = min(mn, __shfl_xor(mn, 8));  mn = min(mn, __shfl_xor(mn, 4));
                    mn = min(mn, __shfl_xor(mn, 2));  mn = min(mn, __shfl_xor(mn, 1));
                    float s = bf2f(xnb[(size_t)mn * D + e]);
                    p = fmaf(0.05f, s, 0.95f * p);
                    float pp = p * p;
                    pp += __shfl_xor(pp, 16); pp += __shfl_xor(pp, 8); pp += __shfl_xor(pp, 4);
                    pp += __shfl_xor(pp, 2);  pp += __shfl_xor(pp, 1);
                    p = p / fmaxf(sqrtf(pp), 1e-12f);
                    if (idx == mn) idx = 0x7fffffff;
                }
            } else {
                // exact fallback: full ballot scan (statistically never)
                for (int ii = 0; ii < N; ii += 64) {
                    unsigned long long m = __ballot(tgt[ii + lane] == c);
                    while (m) {
                        int j = __ffsll(m) - 1;
                        m &= (m - 1);
                        float s = bf2f(xnb[(size_t)(ii + j) * D + e]);
                        p = fmaf(0.05f, s, 0.95f * p);
                        float pp = p * p;
                        pp += __shfl_xor(pp, 16); pp += __shfl_xor(pp, 8); pp += __shfl_xor(pp, 4);
                        pp += __shfl_xor(pp, 2);  pp += __shfl_xor(pp, 1);
                        p = p / fmaxf(sqrtf(pp), 1e-12f);
                    }
                }
            }
            float pp = p * p;
            pp += __shfl_xor(pp, 16); pp += __shfl_xor(pp, 8); pp += __shfl_xor(pp, 4);
            pp += __shfl_xor(pp, 2);  pp += __shfl_xor(pp, 1);
            float pn = p / fmaxf(sqrtf(pp), 1e-8f);
            float kap = fmaxf(kw[c], 0.0f);
            if (lane < D) qb[(size_t)c * D + e] = f2bf(kap * pn);
            if (lane == 0) {
                // log C_d(kap), cancellation-free rearrangement
                float nu = 0.5f * dval - 1.0f;
                float z  = kap / nu, z2 = z * z;
                float sq = sqrtf(1.0f + z2);
                float t  = 1.0f / sq;
                float u1 = (3.0f * t - 5.0f * t * t * t) * (1.0f / 24.0f);
                float lw = dval * (-0.918938533204672742f)
                         + nu * (logf(nu) + log1pf(sq) - sq)
                         + 0.5f * logf(6.2831853071795864f * nu)
                         + 0.25f * log1pf(z2)
                         - log1pf(u1 / nu);
                w[c] = __expf(lw);
            }
        }
    }
    gbar(&bar[1], nblk);

    // ======== P2: full-row MFMA+exp row-sums for this block's 32 samples ========
    __shared__ float Sl[4][32];
    __shared__ float redv[4];
    __shared__ float red2[4];
    __shared__ int lastflag;
    {
        int m = lane & 15, kg = lane >> 4, k0 = kg * 8;
        int s0 = b * 32;
        short8v a0 = *(const short8v*)(xnb + (size_t)(s0 + m) * D + k0);
        short8v a1 = *(const short8v*)(xnb + (size_t)(s0 + 16 + m) * D + k0);
        float4v z = {0.f, 0.f, 0.f, 0.f};
        float4v sa0 = z, sa1 = z;
        int nct = C / 64;                  // class-tiles per wave (32)
        for (int jt = 0; jt < nct; ++jt) {
            int c0 = (wv * nct + jt) * 16;
            short8v bf = *(const short8v*)(qb + (size_t)(c0 + m) * D + k0);
            float wl = w[c0 + m];
            float4v acc0 = __builtin_amdgcn_mfma_f32_16x16x32_bf16(a0, bf, z, 0, 0, 0);
            float4v acc1 = __builtin_amdgcn_mfma_f32_16x16x32_bf16(a1, bf, z, 0, 0, 0);
#pragma unroll
            for (int r = 0; r < 4; ++r) {
                sa0[r] = fmaf(wl, __expf(acc0[r]), sa0[r]);
                sa1[r] = fmaf(wl, __expf(acc1[r]), sa1[r]);
            }
        }
#pragma unroll
        for (int off = 1; off < 16; off <<= 1) {
#pragma unroll
            for (int r = 0; r < 4; ++r) {
                sa0[r] += __shfl_xor(sa0[r], off);
                sa1[r] += __shfl_xor(sa1[r], off);
            }
        }
        if (m == 0) {
#pragma unroll
            for (int r = 0; r < 4; ++r) {
                Sl[wv][kg * 4 + r]      = sa0[r];
                Sl[wv][16 + kg * 4 + r] = sa1[r];
            }
        }
    }
    __syncthreads();
    // NLL for the block's 32 samples: wave wv handles 8 samples, 8 lanes each
    {
        int s_sub = wv * 8 + (lane >> 3);
        int e4 = (lane & 7) * 4;
        int si = b * 32 + s_sub;
        int t = tgt[si];
        ushort4 xv = *(const ushort4*)(xnb + (size_t)si * D + e4);
        ushort4 qv = *(const ushort4*)(qb + (size_t)t * D + e4);
        float d4 = bf2f(xv.x) * bf2f(qv.x);
        d4 = fmaf(bf2f(xv.y), bf2f(qv.y), d4);
        d4 = fmaf(bf2f(xv.z), bf2f(qv.z), d4);
        d4 = fmaf(bf2f(xv.w), bf2f(qv.w), d4);
        d4 += __shfl_xor(d4, 1); d4 += __shfl_xor(d4, 2); d4 += __shfl_xor(d4, 4);
        float val = 0.f;
        if ((lane & 7) == 0) {
            float S = (Sl[0][s_sub] + Sl[1][s_sub]) + (Sl[2][s_sub] + Sl[3][s_sub]);
            val = logf(w[t] * __expf(d4) / S + 1e-6f);
        }
        val += __shfl_xor(val, 8); val += __shfl_xor(val, 16); val += __shfl_xor(val, 32);
        if (lane == 0) redv[wv] = val;
    }
    __syncthreads();
    if (tid == 0) {
        float bp = (redv[0] + redv[1]) + (redv[2] + redv[3]);
        atomicExch((unsigned int*)&part[b], __float_as_uint(bp));   // coherent publish
        __threadfence();
        int old = atomicAdd(done, 1);
        lastflag = (old == nblk - 1) ? 1 : 0;
    }
    __syncthreads();
    if (lastflag) {
        __threadfence();
        float v = 0.f;
        if (tid < nblk)      v += __uint_as_float(atomicAdd((unsigned int*)&part[tid], 0u));
        if (tid + BT < nblk) v += __uint_as_float(atomicAdd((unsigned int*)&part[tid + BT], 0u));
        v += __shfl_xor(v, 1); v += __shfl_xor(v, 2); v += __shfl_xor(v, 4);
        v += __shfl_xor(v, 8); v += __shfl_xor(v, 16); v += __shfl_xor(v, 32);
        if (lane == 0) red2[wv] = v;
        __syncthreads();
        if (tid == 0) out[0] = -((red2[0] + red2[1]) + (red2[2] + red2[3])) / (float)N;
    }
}

extern "C" void kernel_launch(void* const* d_in, const int* in_sizes, int n_in,
                              void* d_out, int out_size, void* d_ws, size_t ws_size,
                              hipStream_t stream) {
    const float* x    = (const float*)d_in[0];   // [N, D]
    const float* kw   = (const float*)d_in[1];   // [C]
    const float* p_in = (const float*)d_in[2];   // [C, D]
    const int*   tgt  = (const int*)d_in[3];     // [N]
    int C = in_sizes[1];
    int N = in_sizes[3];
    float dval = (float)(in_sizes[2] / C);       // == 32
    int nblk = N / 32;                            // 512 blocks (2/CU co-resident)

    // ws layout: [zero region: cnt C | done 1 | bar 8 | pad] then data buffers
    int* cnt  = (int*)d_ws;
    int* done = cnt + C;
    int* bar  = done + 1;
    size_t zbytes = ((size_t)(C + 16) * sizeof(int) + 63) & ~(size_t)63;
    unsigned short* xnb = (unsigned short*)((char*)d_ws + zbytes);  // N*D bf16
    unsigned short* qb  = xnb + (size_t)N * D;                      // C*D bf16
    float* w    = (float*)(qb + (size_t)C * D);                     // C f32
    float* part = w + C;                                            // nblk f32
    int* list2d = (int*)(part + nblk);                              // C*CAP ints
    (void)n_in; (void)out_size; (void)ws_size;

    // node 1: zero cnt/done/barrier counters (re-zeroed every replay)
    hipMemsetAsync(d_ws, 0, (size_t)(C + 16) * sizeof(int), stream);
    // node 2: fused pipeline with grid barriers
    k_mega<<<nblk, BT, 0, stream>>>(x, kw, p_in, tgt, xnb, qb, w, cnt, list2d,
                                    bar, part, done, (float*)d_out, N, C, dval, nblk);
}

// Round 6
// 53.403 us; speedup vs baseline: 2.5131x; 2.5131x over previous
//
#include <hip/hip_runtime.h>
#include <hip/hip_bf16.h>
#include <math.h>

#define D 32
#define CAP 64      // bucket capacity (mid path up to CAP, full-scan beyond)
#define PRE 24      // prefetch fast path (max Poisson(8) count over 2048 classes ~22)
#define SBT 512     // k_score threads (8 waves)

typedef __attribute__((ext_vector_type(8))) short short8v;
typedef __attribute__((ext_vector_type(4))) float float4v;

static __device__ __forceinline__ unsigned short f2bf(float f) {
    union { __hip_bfloat16 h; unsigned short u; } cv;
    cv.h = __float2bfloat16(f);
    return cv.u;
}
static __device__ __forceinline__ float bf2f(unsigned short u) {
    union { float f; unsigned int i; } c;
    c.i = ((unsigned int)u) << 16;
    return c.f;
}

// ---- K1: bucket-scatter sample indices by class (unordered; k_proto sorts) ----
__global__ void k_bucket(const int* __restrict__ tgt, int* __restrict__ cnt,
                         int* __restrict__ list2d, int N) {
    int i = blockIdx.x * blockDim.x + threadIdx.x;
    if (i < N) {
        int t = tgt[i];
        int pos = atomicAdd(&cnt[t], 1);
        if (pos < CAP) list2d[t * CAP + pos] = i;
    }
}

// ---- K2: per-class sequential EMA chain -> qb (bf16, kappa folded), w ----
// Normalizes gathered samples from raw x (f32, eps 1e-12) in-wave.
__global__ void k_proto(const float* __restrict__ x, const int* __restrict__ tgt,
                        const int* __restrict__ list2d, const int* __restrict__ cnt,
                        const float* __restrict__ p_in, const float* __restrict__ kw,
                        unsigned short* __restrict__ qb, float* __restrict__ w,
                        int N, int C, float dval) {
    int wave = (blockIdx.x * blockDim.x + threadIdx.x) >> 6;
    int lane = threadIdx.x & 63;
    if (wave >= C) return;
    int c = wave, e = lane & 31;           // lanes 32-63 mirror 0-31
    float p = p_in[(size_t)c * D + e];
    int count = cnt[c];

    if (count <= PRE) {
        // rank-sort indices in-wave, prefetch, normalize with ILP, then ALU-only chain
        int idx = (lane < count) ? list2d[c * CAP + lane] : 0x7fffffff;
        int rank = 0;
        for (int j = 0; j < count; ++j) {
            int v = __shfl(idx, j);
            rank += (v < idx) ? 1 : 0;
        }
        int sorted = 0;
        for (int j = 0; j < count; ++j) {
            int v = __shfl(idx, j); int r = __shfl(rank, j);
            if (r == lane) sorted = v;
        }
        float vals[PRE];
#pragma unroll
        for (int it = 0; it < PRE; ++it)
            if (it < count) {
                int si = __shfl(sorted, it);
                vals[it] = x[(size_t)si * D + e];      // independent loads
            }
#pragma unroll
        for (int it = 0; it < PRE; ++it)
            if (it < count) {                           // independent normalizes (ILP)
                float v = vals[it];
                float ss = v * v;
                ss += __shfl_xor(ss, 16); ss += __shfl_xor(ss, 8); ss += __shfl_xor(ss, 4);
                ss += __shfl_xor(ss, 2);  ss += __shfl_xor(ss, 1);
                vals[it] = v / fmaxf(sqrtf(ss), 1e-12f);
            }
#pragma unroll
        for (int it = 0; it < PRE; ++it)
            if (it < count) {                           // sequential EMA chain
                p = fmaf(0.05f, vals[it], 0.95f * p);
                float pp = p * p;
                pp += __shfl_xor(pp, 16); pp += __shfl_xor(pp, 8); pp += __shfl_xor(pp, 4);
                pp += __shfl_xor(pp, 2);  pp += __shfl_xor(pp, 1);
                p = p / fmaxf(sqrtf(pp), 1e-12f);
            }
    } else if (count <= CAP) {
        // exact mid path: min-extract ordered chain
        int idx = (lane < count) ? list2d[c * CAP + lane] : 0x7fffffff;
        for (int it = 0; it < count; ++it) {
            int mn = idx;
            mn = min(mn, __shfl_xor(mn, 32)); mn = min(mn, __shfl_xor(mn, 16));
            mn = min(mn, __shfl_xor(mn, 8));  mn = min(mn, __shfl_xor(mn, 4));
            mn = min(mn, __shfl_xor(mn, 2));  mn = min(mn, __shfl_xor(mn, 1));
            float v = x[(size_t)mn * D + e];
            float ss = v * v;
            ss += __shfl_xor(ss, 16); ss += __shfl_xor(ss, 8); ss += __shfl_xor(ss, 4);
            ss += __shfl_xor(ss, 2);  ss += __shfl_xor(ss, 1);
            float s = v / fmaxf(sqrtf(ss), 1e-12f);
            p = fmaf(0.05f, s, 0.95f * p);
            float pp = p * p;
            pp += __shfl_xor(pp, 16); pp += __shfl_xor(pp, 8); pp += __shfl_xor(pp, 4);
            pp += __shfl_xor(pp, 2);  pp += __shfl_xor(pp, 1);
            p = p / fmaxf(sqrtf(pp), 1e-12f);
            if (idx == mn) idx = 0x7fffffff;
        }
    } else {
        // exact fallback: full ballot scan (statistically never at N/C=8)
        for (int ii = 0; ii < N; ii += 64) {
            unsigned long long m = __ballot(tgt[ii + lane] == c);
            while (m) {
                int j = __ffsll(m) - 1;
                m &= (m - 1);
                float v = x[(size_t)(ii + j) * D + e];
                float ss = v * v;
                ss += __shfl_xor(ss, 16); ss += __shfl_xor(ss, 8); ss += __shfl_xor(ss, 4);
                ss += __shfl_xor(ss, 2);  ss += __shfl_xor(ss, 1);
                float s = v / fmaxf(sqrtf(ss), 1e-12f);
                p = fmaf(0.05f, s, 0.95f * p);
                float pp = p * p;
                pp += __shfl_xor(pp, 16); pp += __shfl_xor(pp, 8); pp += __shfl_xor(pp, 4);
                pp += __shfl_xor(pp, 2);  pp += __shfl_xor(pp, 1);
                p = p / fmaxf(sqrtf(pp), 1e-12f);
            }
        }
    }

    float pp = p * p;
    pp += __shfl_xor(pp, 16); pp += __shfl_xor(pp, 8); pp += __shfl_xor(pp, 4);
    pp += __shfl_xor(pp, 2);  pp += __shfl_xor(pp, 1);
    float pn = p / fmaxf(sqrtf(pp), 1e-8f);
    float kap = fmaxf(kw[c], 0.0f);
    if (lane < D) qb[(size_t)c * D + e] = f2bf(kap * pn);
    if (lane == 0) {
        // log C_d(kap), cancellation-free rearrangement
        float nu = 0.5f * dval - 1.0f;
        float z  = kap / nu, z2 = z * z;
        float sq = sqrtf(1.0f + z2);
        float t  = 1.0f / sq;
        float u1 = (3.0f * t - 5.0f * t * t * t) * (1.0f / 24.0f);
        float lw = dval * (-0.918938533204672742f)
                 + nu * (logf(nu) + log1pf(sq) - sq)
                 + 0.5f * logf(6.2831853071795864f * nu)
                 + 0.25f * log1pf(z2)
                 - log1pf(u1 / nu);
        w[c] = __expf(lw);
    }
}

// ---- K3: per-block full-row MFMA + exp rowsum + target-logit capture + NLL ----
// 512 blocks x 8 waves; block owns 32 samples; wave wv owns classes [wv*256,(wv+1)*256)
__global__ void __launch_bounds__(SBT)
k_score(const float* __restrict__ x, const int* __restrict__ tgt,
        const unsigned short* __restrict__ qb, const float* __restrict__ w,
        float* __restrict__ part, int* __restrict__ done, float* __restrict__ out,
        int N, int C, int nblk) {
    __shared__ float Sl[8][32];
    __shared__ float Lt[32];
    __shared__ float redp[8];
    __shared__ int lastflag;
    int tid = threadIdx.x, b = blockIdx.x;
    int lane = tid & 63, wv = tid >> 6;
    int m = lane & 15, kg = lane >> 4, k0 = kg * 8;
    int s0 = b * 32;

    // --- build normalized bf16 A fragments straight from x (cos eps 1e-8) ---
    short8v a0, a1;
    {
        const float4* px = (const float4*)(x + (size_t)(s0 + m) * D + k0);
        float4 u0 = px[0], u1 = px[1];
        float ss = u0.x*u0.x + u0.y*u0.y + u0.z*u0.z + u0.w*u0.w
                 + u1.x*u1.x + u1.y*u1.y + u1.z*u1.z + u1.w*u1.w;
        ss += __shfl_xor(ss, 16); ss += __shfl_xor(ss, 32);   // combine 4 kg-partials
        float inv = 1.0f / fmaxf(sqrtf(ss), 1e-8f);
        a0[0] = (short)f2bf(u0.x*inv); a0[1] = (short)f2bf(u0.y*inv);
        a0[2] = (short)f2bf(u0.z*inv); a0[3] = (short)f2bf(u0.w*inv);
        a0[4] = (short)f2bf(u1.x*inv); a0[5] = (short)f2bf(u1.y*inv);
        a0[6] = (short)f2bf(u1.z*inv); a0[7] = (short)f2bf(u1.w*inv);
    }
    {
        const float4* px = (const float4*)(x + (size_t)(s0 + 16 + m) * D + k0);
        float4 u0 = px[0], u1 = px[1];
        float ss = u0.x*u0.x + u0.y*u0.y + u0.z*u0.z + u0.w*u0.w
                 + u1.x*u1.x + u1.y*u1.y + u1.z*u1.z + u1.w*u1.w;
        ss += __shfl_xor(ss, 16); ss += __shfl_xor(ss, 32);
        float inv = 1.0f / fmaxf(sqrtf(ss), 1e-8f);
        a1[0] = (short)f2bf(u0.x*inv); a1[1] = (short)f2bf(u0.y*inv);
        a1[2] = (short)f2bf(u0.z*inv); a1[3] = (short)f2bf(u0.w*inv);
        a1[4] = (short)f2bf(u1.x*inv); a1[5] = (short)f2bf(u1.y*inv);
        a1[6] = (short)f2bf(u1.z*inv); a1[7] = (short)f2bf(u1.w*inv);
    }

    // targets of the 8 C/D rows this lane produces (4 in a0-group, 4 in a1-group)
    int tr0[4], tr1[4];
#pragma unroll
    for (int r = 0; r < 4; ++r) {
        tr0[r] = tgt[s0 + kg * 4 + r];
        tr1[r] = tgt[s0 + 16 + kg * 4 + r];
    }

    float4v z = {0.f, 0.f, 0.f, 0.f};
    float4v sa0 = z, sa1 = z;
    int ntiles = C / (16 * 8);             // 16 class-tiles per wave
    for (int jt = 0; jt < ntiles; ++jt) {
        int c0 = (wv * ntiles + jt) * 16;
        short8v bfrag = *(const short8v*)(qb + (size_t)(c0 + m) * D + k0);
        float wl = w[c0 + m];
        float4v acc0 = __builtin_amdgcn_mfma_f32_16x16x32_bf16(a0, bfrag, z, 0, 0, 0);
        float4v acc1 = __builtin_amdgcn_mfma_f32_16x16x32_bf16(a1, bfrag, z, 0, 0, 0);
#pragma unroll
        for (int r = 0; r < 4; ++r) {
            if (c0 + m == tr0[r]) Lt[kg * 4 + r] = acc0[r];        // target logit
            if (c0 + m == tr1[r]) Lt[16 + kg * 4 + r] = acc1[r];
            sa0[r] = fmaf(wl, __expf(acc0[r]), sa0[r]);
            sa1[r] = fmaf(wl, __expf(acc1[r]), sa1[r]);
        }
    }
#pragma unroll
    for (int off = 1; off < 16; off <<= 1) {
#pragma unroll
        for (int r = 0; r < 4; ++r) {
            sa0[r] += __shfl_xor(sa0[r], off);
            sa1[r] += __shfl_xor(sa1[r], off);
        }
    }
    if (m == 0) {
#pragma unroll
        for (int r = 0; r < 4; ++r) {
            Sl[wv][kg * 4 + r]      = sa0[r];
            Sl[wv][16 + kg * 4 + r] = sa1[r];
        }
    }
    __syncthreads();

    // --- per-sample NLL (wave 0, lanes 0-31) + block partial ---
    float val = 0.f;
    if (wv == 0) {
        if (lane < 32) {
            int s = lane;
            float S = ((Sl[0][s] + Sl[1][s]) + (Sl[2][s] + Sl[3][s]))
                    + ((Sl[4][s] + Sl[5][s]) + (Sl[6][s] + Sl[7][s]));
            int t = tgt[s0 + s];
            val = logf(w[t] * __expf(Lt[s]) / S + 1e-6f);
        }
        val += __shfl_xor(val, 32); val += __shfl_xor(val, 16); val += __shfl_xor(val, 8);
        val += __shfl_xor(val, 4);  val += __shfl_xor(val, 2);  val += __shfl_xor(val, 1);
    }
    if (tid == 0) {
        atomicExch((unsigned int*)&part[b], __float_as_uint(val));  // coherent publish
        __threadfence();
        int old = atomicAdd(done, 1);
        lastflag = (old == nblk - 1) ? 1 : 0;
    }
    __syncthreads();

    // --- last block: deterministic fixed-order final reduce ---
    if (lastflag) {
        __threadfence();
        float v = (tid < nblk) ? __uint_as_float(atomicAdd((unsigned int*)&part[tid], 0u)) : 0.f;
        v += __shfl_xor(v, 32); v += __shfl_xor(v, 16); v += __shfl_xor(v, 8);
        v += __shfl_xor(v, 4);  v += __shfl_xor(v, 2);  v += __shfl_xor(v, 1);
        if (lane == 0) redp[wv] = v;
        __syncthreads();
        if (tid == 0)
            out[0] = -(((redp[0] + redp[1]) + (redp[2] + redp[3]))
                     + ((redp[4] + redp[5]) + (redp[6] + redp[7]))) / (float)N;
    }
}

extern "C" void kernel_launch(void* const* d_in, const int* in_sizes, int n_in,
                              void* d_out, int out_size, void* d_ws, size_t ws_size,
                              hipStream_t stream) {
    const float* x    = (const float*)d_in[0];   // [N, D]
    const float* kw   = (const float*)d_in[1];   // [C]
    const float* p_in = (const float*)d_in[2];   // [C, D]
    const int*   tgt  = (const int*)d_in[3];     // [N]
    int C = in_sizes[1];
    int N = in_sizes[3];
    float dval = (float)(in_sizes[2] / C);       // == 32
    int nblk = N / 32;                            // 512 score blocks

    // ws layout: [zero region: cnt C | done 1 | pad to 64B] qb | w | part | list2d
    int* cnt  = (int*)d_ws;
    int* done = cnt + C;
    size_t zbytes = ((size_t)(C + 8) * sizeof(int) + 63) & ~(size_t)63;
    unsigned short* qb = (unsigned short*)((char*)d_ws + zbytes);   // C*D bf16
    float* w    = (float*)(qb + (size_t)C * D);                     // C f32
    float* part = w + C;                                            // nblk f32
    int* list2d = (int*)(part + nblk);                              // C*CAP ints
    (void)n_in; (void)out_size; (void)ws_size;

    // node 1: zero cnt + done (runs every replay)
    hipMemsetAsync(d_ws, 0, (size_t)(C + 8) * sizeof(int), stream);
    // node 2: bucket-scatter
    k_bucket<<<(N + 255) / 256, 256, 0, stream>>>(tgt, cnt, list2d, N);
    // node 3: per-class EMA chains -> qb, w
    k_proto<<<(C * 64 + 255) / 256, 256, 0, stream>>>(x, tgt, list2d, cnt, p_in, kw, qb, w, N, C, dval);
    // node 4: full-row score + NLL + final reduce
    k_score<<<nblk, SBT, 0, stream>>>(x, tgt, qb, w, part, done, (float*)d_out, N, C, nblk);
}